// Round 9
// baseline (2221.226 us; speedup 1.0000x reference)
//
#include <hip/hip_runtime.h>

// MultiHeadAttentionCell: B=2, L=2048, H=16, C=64, fp32 in/out.
// Outputs (concat in d_out): context_vec (B,L,H*C)=4194304 | scores (B,H,L,L)=134217728 | attn (B,H,L,L)=134217728
// scores = Q K^T + edge ; attn = softmax(where(mask, scores/8, -1e18)) * mask ; ctx = attn @ V
//
// ROUND 9 = INSTRUMENTATION ROUND. k_main is byte-identical to R7 (best: 1684us).
// k_main is idempotent (pure function of inputs), so it is launched TWICE:
// the duplicate forces both k_main dispatches into rocprof's top-5 with full
// counters (never observed since R1 -- every counter row so far was the harness
// fill). k_norm cost falls out as dur - fill - 2*k_main. Expected dur ~2350us
// (deliberate one-round cost to buy the per-kernel map).
// k_norm: nt LOAD removed (no-reuse loads gain nothing from nt; store stays nt).

typedef __attribute__((ext_vector_type(8))) short bf16x8;  // 8 bf16 = 4 VGPRs
typedef __attribute__((ext_vector_type(4))) float f32x4;
typedef __attribute__((ext_vector_type(4))) int   i32x4;

#define LQ 2048
#define NH 16
#define CD 64

__device__ inline short f2bf(float x) {
    union { float f; unsigned u; } v; v.f = x;
    unsigned r = v.u + 0x7FFFu + ((v.u >> 16) & 1u);   // RTNE
    return (short)(r >> 16);
}

__device__ inline bf16x8 pack8(f32x4 a, f32x4 b) {
    bf16x8 r;
    r[0] = f2bf(a[0]); r[1] = f2bf(a[1]); r[2] = f2bf(a[2]); r[3] = f2bf(a[3]);
    r[4] = f2bf(b[0]); r[5] = f2bf(b[1]); r[6] = f2bf(b[2]); r[7] = f2bf(b[3]);
    return r;
}

// LDS-visibility barrier WITHOUT __syncthreads' vmcnt(0) drain.
__device__ inline void lds_barrier() {
    asm volatile("s_waitcnt lgkmcnt(0)" ::: "memory");
    __builtin_amdgcn_s_barrier();
}

// ---------------- Kernel 1: fused scores + unnormalized attn + PV + l -----
// grid: 1024 (XCD-swizzled -> 32 i-tiles x 32 z), block 256 (4 waves).
__global__ __launch_bounds__(256, 4)
void k_main(const float* __restrict__ q, const float* __restrict__ kk,
            const float* __restrict__ v, const int* __restrict__ mask,
            const float* __restrict__ edge,
            float* __restrict__ sc, float* __restrict__ attn,
            float* __restrict__ ctx, float* __restrict__ invout)
{
    __shared__ short Ks[64][66];       // stride 33 dw === 1 mod 32: ~2-way banks on b128
    __shared__ short Vt[64][66];       // V^T: Vt[c][j_local]
    __shared__ short Wt[4][16][66];    // per-wave bf16 p slab: Wt[wave][i_local=mm][j_local]

    // XCD-chunk swizzle (bijective, 1024 % 8 == 0): XCD x gets 4 contiguous z-slices.
    const int flat = blockIdx.x;
    const int L = (flat & 7) * 128 + (flat >> 3);
    const int z = L >> 5;
    const int i0 = (L & 31) * 64;
    const int b = z & 1, h = z >> 1;

    const int tid = threadIdx.x;
    const int r = tid >> 2, seg = (tid & 3) * 16;
    const int wave = tid >> 6, lane = tid & 63;
    const int quad = lane >> 4, mm = lane & 15;

    const int gi = i0 + wave * 16 + mm;            // this lane's query row
    // Q as B-fragment: B[k=quad*8+t][n=mm] = Q[gi][k] (direct from global, one-time)
    const float* qp = q + ((size_t)((b * LQ + gi) * NH + h)) * CD;
    bf16x8 qa0 = pack8(*(const f32x4*)(qp + quad * 8), *(const f32x4*)(qp + quad * 8 + 4));
    bf16x8 qa1 = pack8(*(const f32x4*)(qp + 32 + quad * 8), *(const f32x4*)(qp + 32 + quad * 8 + 4));

    const float* erow = edge + ((size_t)(h * LQ + gi)) * LQ;
    const int*   mrow = mask + ((size_t)(b * LQ + gi)) * LQ;
    const size_t srow = ((size_t)((b * NH + h) * LQ + gi)) * LQ;   // sc/attn row base

    // prefetch tile 0: edge + mask
    f32x4 ev[4]; i32x4 mv[4];
    #pragma unroll
    for (int jt = 0; jt < 4; ++jt) {
        ev[jt] = *(const f32x4*)(erow + jt * 16 + quad * 4);
        mv[jt] = *(const i32x4*)(mrow + jt * 16 + quad * 4);
    }
    // prefetch tile 0: K/V rows into regs
    f32x4 kr[4], vr[4];
    {
        const float* kp = kk + ((size_t)((b * LQ + r) * NH + h)) * CD + seg;
        const float* vp = v  + ((size_t)((b * LQ + r) * NH + h)) * CD + seg;
        #pragma unroll
        for (int u = 0; u < 4; ++u) { kr[u] = ((const f32x4*)kp)[u]; vr[u] = ((const f32x4*)vp)[u]; }
    }

    float lacc = 0.f;
    f32x4 cacc[4] = { {0,0,0,0}, {0,0,0,0}, {0,0,0,0}, {0,0,0,0} };

    for (int jb = 0; jb < 32; ++jb) {
        const int j0 = jb * 64;
        // stage current tile from prefetched regs (counted vmcnt wait at f2bf use)
        #pragma unroll
        for (int u = 0; u < 4; ++u) {
            *(short4*)&Ks[r][seg + u * 4] =
                make_short4(f2bf(kr[u][0]), f2bf(kr[u][1]), f2bf(kr[u][2]), f2bf(kr[u][3]));
            Vt[seg + u * 4 + 0][r] = f2bf(vr[u][0]);
            Vt[seg + u * 4 + 1][r] = f2bf(vr[u][1]);
            Vt[seg + u * 4 + 2][r] = f2bf(vr[u][2]);
            Vt[seg + u * 4 + 3][r] = f2bf(vr[u][3]);
        }
        lds_barrier();                 // writes visible; NO global drain

        // swapped QK^T: acc[jt][reg] = S[gi][j0 + jt*16 + quad*4 + reg]
        f32x4 acc[4];
        #pragma unroll
        for (int jt = 0; jt < 4; ++jt) {
            bf16x8 k0 = *(const bf16x8*)&Ks[jt * 16 + mm][quad * 8];
            bf16x8 k1 = *(const bf16x8*)&Ks[jt * 16 + mm][32 + quad * 8];
            f32x4 a = {0.f, 0.f, 0.f, 0.f};
            a = __builtin_amdgcn_mfma_f32_16x16x32_bf16(k0, qa0, a, 0, 0, 0);
            a = __builtin_amdgcn_mfma_f32_16x16x32_bf16(k1, qa1, a, 0, 0, 0);
            acc[jt] = a;
        }

        // issue next tile's K/V loads (stay in flight across raw barriers)
        if (jb < 31) {
            const float* kp = kk + ((size_t)((b * LQ + j0 + 64 + r) * NH + h)) * CD + seg;
            const float* vp = v  + ((size_t)((b * LQ + j0 + 64 + r) * NH + h)) * CD + seg;
            #pragma unroll
            for (int u = 0; u < 4; ++u) { kr[u] = ((const f32x4*)kp)[u]; vr[u] = ((const f32x4*)vp)[u]; }
        }

        // register epilogue: sc, unnormalized p -> attn + Wt + lacc
        #pragma unroll
        for (int jt = 0; jt < 4; ++jt) {
            const int jl = jt * 16 + quad * 4;
            f32x4 s4 = acc[jt] + ev[jt];
            *(f32x4*)(sc + srow + j0 + jl) = s4;
            f32x4 p;
            p[0] = mv[jt][0] ? __expf(s4[0] * 0.125f) : 0.f;
            p[1] = mv[jt][1] ? __expf(s4[1] * 0.125f) : 0.f;
            p[2] = mv[jt][2] ? __expf(s4[2] * 0.125f) : 0.f;
            p[3] = mv[jt][3] ? __expf(s4[3] * 0.125f) : 0.f;
            *(f32x4*)(attn + srow + j0 + jl) = p;
            *(short4*)&Wt[wave][mm][jl] = make_short4(f2bf(p[0]), f2bf(p[1]), f2bf(p[2]), f2bf(p[3]));
            lacc += (p[0] + p[1]) + (p[2] + p[3]);
        }

        if (jb < 31) {     // prefetch next tile's edge+mask (in flight across barriers)
            #pragma unroll
            for (int jt = 0; jt < 4; ++jt) {
                ev[jt] = *(const f32x4*)(erow + j0 + 64 + jt * 16 + quad * 4);
                mv[jt] = *(const i32x4*)(mrow + j0 + 64 + jt * 16 + quad * 4);
            }
        }

        // PV (unnormalized): A = Wt (m=i_local=mm), B = Vt (n=c). Wave-internal RAW on Wt.
        #pragma unroll
        for (int kt = 0; kt < 2; ++kt) {
            bf16x8 aw = *(const bf16x8*)&Wt[wave][mm][kt * 32 + quad * 8];
            #pragma unroll
            for (int nt = 0; nt < 4; ++nt) {
                bf16x8 bb = *(const bf16x8*)&Vt[nt * 16 + mm][kt * 32 + quad * 8];
                cacc[nt] = __builtin_amdgcn_mfma_f32_16x16x32_bf16(aw, bb, cacc[nt], 0, 0, 0);
            }
        }
        lds_barrier();                 // readers done; next iter may overwrite Ks/Vt
    }

    // row sum -> inv. After the two xors every lane holds its own row's total.
    lacc += __shfl_xor(lacc, 16, 64);
    lacc += __shfl_xor(lacc, 32, 64);
    const float inv = (lacc > 0.f) ? 1.f / lacc : 0.f;   // l==0 iff all-masked row -> 0
    if (quad == 0)
        invout[(size_t)(b * NH + h) * LQ + gi] = inv;

    // ctx rows in C-layout are quad*4+reg -> fetch those rows' inv via shfl from lane (quad*4+reg)
    float inv4[4];
    #pragma unroll
    for (int reg = 0; reg < 4; ++reg)
        inv4[reg] = __shfl(inv, quad * 4 + reg, 64);

    const int irow = i0 + wave * 16 + quad * 4;
    #pragma unroll
    for (int nt = 0; nt < 4; ++nt) {
        const int c = nt * 16 + mm;
        #pragma unroll
        for (int reg = 0; reg < 4; ++reg) {
            const int i = irow + reg;
            ctx[((size_t)(b * LQ + i)) * (NH * CD) + h * CD + c] = cacc[nt][reg] * inv4[reg];
        }
    }
}

// ---------------- Kernel 2: attn *= inv[row] (pure streaming) -------------
__global__ __launch_bounds__(256)
void k_norm(float* __restrict__ attn, const float* __restrict__ inv)
{
    const size_t total4 = (size_t)2 * NH * LQ * LQ / 4;   // 33554432 float4s
    size_t idx = (size_t)blockIdx.x * 256 + threadIdx.x;
    const size_t stride = (size_t)gridDim.x * 256;
    for (; idx < total4; idx += stride) {
        const float iv = inv[(idx * 4) >> 11];            // row = elem >> 11
        f32x4 w = *((const f32x4*)attn + idx);            // plain load (nt gave nothing)
        w *= iv;
        __builtin_nontemporal_store(w, (f32x4*)attn + idx);
    }
}

extern "C" void kernel_launch(void* const* d_in, const int* in_sizes, int n_in,
                              void* d_out, int out_size, void* d_ws, size_t ws_size,
                              hipStream_t stream) {
    const float* q    = (const float*)d_in[0];
    const float* k    = (const float*)d_in[1];
    const float* v    = (const float*)d_in[2];
    const int*   mask = (const int*)d_in[3];    // bool -> int32 per harness contract
    const float* edge = (const float*)d_in[4];

    float* out = (float*)d_out;
    float* ctx = out;                            // 2*2048*1024
    float* sc  = out + 4194304;                  // scores (B,H,L,L)
    float* at  = sc + 134217728;                 // attn   (B,H,L,L)

    float* inv = (float*)d_ws;                   // 65536 row inverses = 256 KB

    // INSTRUMENTATION: k_main is idempotent; launch twice so both dispatches
    // surface in rocprof's top-5 with full PMC rows (fills are ~690us).
    k_main<<<dim3(1024), 256, 0, stream>>>(q, k, v, mask, edge, sc, at, ctx, inv);
    k_main<<<dim3(1024), 256, 0, stream>>>(q, k, v, mask, edge, sc, at, ctx, inv);
    k_norm<<<dim3(2048), 256, 0, stream>>>(at, inv);
}

// Round 10
// 1646.464 us; speedup vs baseline: 1.3491x; 1.3491x over previous
//
#include <hip/hip_runtime.h>

// MultiHeadAttentionCell: B=2, L=2048, H=16, C=64, fp32 in/out.
// Outputs (concat in d_out): context_vec (B,L,H*C)=4194304 | scores (B,H,L,L)=134217728 | attn (B,H,L,L)=134217728
// scores = Q K^T + edge ; attn = softmax(where(mask, scores/8, -1e18)) * mask ; ctx = attn @ V
//
// Round 10: ONE kernel, TWO phases per block; k_norm (measured ~452us @2.4TB/s, R9) deleted.
// Each block owns rows [i0,i0+64) and sweeps all j, so it can learn l BEFORE writing attn:
//   Phase A: QK^T sweep (dbuf K tile, 1 barrier/iter), writes sc (needs no norm),
//            accumulates l = sum_j exp((s+e)/8)*mask per row. No other stores.
//   Phase B: recomputes the SAME QK^T (bitwise-identical MFMA+edge -> consistent),
//            writes attn = p * (1/l) ONCE (the 1.07GB attn round-trip is gone),
//            PV with normalized weights -> ctx needs no final scaling.
// K re-read in B is L2-resident (512KB/head; XCD swizzle keeps blocks on-die).
// Edge is re-read in B (+268MB HBM) -- 4x cheaper than the attn round-trip.
// Raw lgkmcnt-only barriers (R7), K/V + edge/mask register prefetch (R7),
// XCD chunk swizzle (R7). No max-subtraction: scores/8 ~ N(0,1)+edge/8, exp() safe in fp32.

typedef __attribute__((ext_vector_type(8))) short bf16x8;  // 8 bf16 = 4 VGPRs
typedef __attribute__((ext_vector_type(4))) float f32x4;
typedef __attribute__((ext_vector_type(4))) int   i32x4;

#define LQ 2048
#define NH 16
#define CD 64

__device__ inline short f2bf(float x) {
    union { float f; unsigned u; } v; v.f = x;
    unsigned r = v.u + 0x7FFFu + ((v.u >> 16) & 1u);   // RTNE
    return (short)(r >> 16);
}

__device__ inline bf16x8 pack8(f32x4 a, f32x4 b) {
    bf16x8 r;
    r[0] = f2bf(a[0]); r[1] = f2bf(a[1]); r[2] = f2bf(a[2]); r[3] = f2bf(a[3]);
    r[4] = f2bf(b[0]); r[5] = f2bf(b[1]); r[6] = f2bf(b[2]); r[7] = f2bf(b[3]);
    return r;
}

// LDS-visibility barrier WITHOUT __syncthreads' vmcnt(0) drain.
__device__ inline void lds_barrier() {
    asm volatile("s_waitcnt lgkmcnt(0)" ::: "memory");
    __builtin_amdgcn_s_barrier();
}

// grid: 1024 (XCD-swizzled -> 32 i-tiles x 32 z=h*2+b), block 256 (4 waves).
__global__ __launch_bounds__(256, 4)
void k_attn(const float* __restrict__ q, const float* __restrict__ kk,
            const float* __restrict__ v, const int* __restrict__ mask,
            const float* __restrict__ edge,
            float* __restrict__ sc, float* __restrict__ attn,
            float* __restrict__ ctx)
{
    __shared__ short KsD[2][64][66];   // double-buffered K tile (phase A: 1 barrier/iter)
    __shared__ short Vt[64][66];       // V^T: Vt[c][j_local] (phase B)
    __shared__ short Wt[4][16][66];    // per-wave bf16 weight slab (phase B)
    // 33.0 KB total -> 4 blocks/CU

    // XCD-chunk swizzle (bijective, 1024 % 8 == 0): XCD x gets 4 contiguous z-slices.
    const int flat = blockIdx.x;
    const int L = (flat & 7) * 128 + (flat >> 3);
    const int z = L >> 5;
    const int i0 = (L & 31) * 64;
    const int b = z & 1, h = z >> 1;

    const int tid = threadIdx.x;
    const int r = tid >> 2, seg = (tid & 3) * 16;
    const int wave = tid >> 6, lane = tid & 63;
    const int quad = lane >> 4, mm = lane & 15;

    const int gi = i0 + wave * 16 + mm;            // this lane's query row
    // Q as B-fragment: B[k=quad*8+t][n=mm] = Q[gi][k]
    const float* qp = q + ((size_t)((b * LQ + gi) * NH + h)) * CD;
    bf16x8 qa0 = pack8(*(const f32x4*)(qp + quad * 8), *(const f32x4*)(qp + quad * 8 + 4));
    bf16x8 qa1 = pack8(*(const f32x4*)(qp + 32 + quad * 8), *(const f32x4*)(qp + 32 + quad * 8 + 4));

    const float* erow = edge + ((size_t)(h * LQ + gi)) * LQ;
    const int*   mrow = mask + ((size_t)(b * LQ + gi)) * LQ;
    const size_t srow = ((size_t)((b * NH + h) * LQ + gi)) * LQ;   // sc/attn row base

    const float* kbase = kk + ((size_t)((b * LQ + r) * NH + h)) * CD + seg;
    const float* vbase = v  + ((size_t)((b * LQ + r) * NH + h)) * CD + seg;
    const size_t kstep = (size_t)64 * NH * CD;     // 64 rows of K/V

    // edge/mask tile 0
    f32x4 ev[4]; i32x4 mv[4];
    #pragma unroll
    for (int jt = 0; jt < 4; ++jt) {
        ev[jt] = *(const f32x4*)(erow + jt * 16 + quad * 4);
        mv[jt] = *(const i32x4*)(mrow + jt * 16 + quad * 4);
    }

    // ================= Phase A: row sums + sc =================
    f32x4 kr[4];
    #pragma unroll
    for (int u = 0; u < 4; ++u) kr[u] = ((const f32x4*)kbase)[u];
    #pragma unroll
    for (int u = 0; u < 4; ++u)    // stage buf0 = K[0]
        *(short4*)&KsD[0][r][seg + u * 4] =
            make_short4(f2bf(kr[u][0]), f2bf(kr[u][1]), f2bf(kr[u][2]), f2bf(kr[u][3]));
    #pragma unroll
    for (int u = 0; u < 4; ++u) kr[u] = ((const f32x4*)(kbase + kstep))[u];   // K[1]
    lds_barrier();

    float lacc = 0.f;
    for (int jb = 0; jb < 32; ++jb) {
        const int j0 = jb * 64;
        const int cur = jb & 1;
        if (jb < 31) {     // stage next buffer; issue K[jb+2]
            #pragma unroll
            for (int u = 0; u < 4; ++u)
                *(short4*)&KsD[cur ^ 1][r][seg + u * 4] =
                    make_short4(f2bf(kr[u][0]), f2bf(kr[u][1]), f2bf(kr[u][2]), f2bf(kr[u][3]));
            if (jb < 30) {
                const float* kp = kbase + kstep * (jb + 2);
                #pragma unroll
                for (int u = 0; u < 4; ++u) kr[u] = ((const f32x4*)kp)[u];
            }
        }
        // swapped QK^T: acc[jt][reg] = S[gi][j0 + jt*16 + quad*4 + reg]
        f32x4 acc[4];
        #pragma unroll
        for (int jt = 0; jt < 4; ++jt) {
            bf16x8 k0 = *(const bf16x8*)&KsD[cur][jt * 16 + mm][quad * 8];
            bf16x8 k1 = *(const bf16x8*)&KsD[cur][jt * 16 + mm][32 + quad * 8];
            f32x4 a = {0.f, 0.f, 0.f, 0.f};
            a = __builtin_amdgcn_mfma_f32_16x16x32_bf16(k0, qa0, a, 0, 0, 0);
            a = __builtin_amdgcn_mfma_f32_16x16x32_bf16(k1, qa1, a, 0, 0, 0);
            acc[jt] = a;
        }
        #pragma unroll
        for (int jt = 0; jt < 4; ++jt) {
            f32x4 s4 = acc[jt] + ev[jt];
            *(f32x4*)(sc + srow + j0 + jt * 16 + quad * 4) = s4;
            lacc += (mv[jt][0] ? __expf(s4[0] * 0.125f) : 0.f)
                  + (mv[jt][1] ? __expf(s4[1] * 0.125f) : 0.f)
                  + (mv[jt][2] ? __expf(s4[2] * 0.125f) : 0.f)
                  + (mv[jt][3] ? __expf(s4[3] * 0.125f) : 0.f);
        }
        if (jb < 31) {
            #pragma unroll
            for (int jt = 0; jt < 4; ++jt) {
                ev[jt] = *(const f32x4*)(erow + j0 + 64 + jt * 16 + quad * 4);
                mv[jt] = *(const i32x4*)(mrow + j0 + 64 + jt * 16 + quad * 4);
            }
        }
        lds_barrier();     // dbuf: single barrier covers "next staged" + "cur reads done"
    }

    // row total over the 4 quads sharing this mm -> every lane holds its row's inv
    lacc += __shfl_xor(lacc, 16, 64);
    lacc += __shfl_xor(lacc, 32, 64);
    const float inv = (lacc > 0.f) ? 1.f / lacc : 0.f;   // l==0 iff all-masked row -> 0

    // ================= Phase B: attn (normalized) + PV =================
    f32x4 vr[4];
    #pragma unroll
    for (int u = 0; u < 4; ++u) { kr[u] = ((const f32x4*)kbase)[u]; vr[u] = ((const f32x4*)vbase)[u]; }
    #pragma unroll
    for (int jt = 0; jt < 4; ++jt) {
        ev[jt] = *(const f32x4*)(erow + jt * 16 + quad * 4);
        mv[jt] = *(const i32x4*)(mrow + jt * 16 + quad * 4);
    }
    f32x4 cacc[4] = { {0,0,0,0}, {0,0,0,0}, {0,0,0,0}, {0,0,0,0} };

    for (int jb = 0; jb < 32; ++jb) {
        const int j0 = jb * 64;
        #pragma unroll
        for (int u = 0; u < 4; ++u) {
            *(short4*)&KsD[0][r][seg + u * 4] =
                make_short4(f2bf(kr[u][0]), f2bf(kr[u][1]), f2bf(kr[u][2]), f2bf(kr[u][3]));
            Vt[seg + u * 4 + 0][r] = f2bf(vr[u][0]);
            Vt[seg + u * 4 + 1][r] = f2bf(vr[u][1]);
            Vt[seg + u * 4 + 2][r] = f2bf(vr[u][2]);
            Vt[seg + u * 4 + 3][r] = f2bf(vr[u][3]);
        }
        lds_barrier();                 // writes visible; NO global drain

        f32x4 acc[4];                  // identical MFMA as phase A -> bitwise-same s4
        #pragma unroll
        for (int jt = 0; jt < 4; ++jt) {
            bf16x8 k0 = *(const bf16x8*)&KsD[0][jt * 16 + mm][quad * 8];
            bf16x8 k1 = *(const bf16x8*)&KsD[0][jt * 16 + mm][32 + quad * 8];
            f32x4 a = {0.f, 0.f, 0.f, 0.f};
            a = __builtin_amdgcn_mfma_f32_16x16x32_bf16(k0, qa0, a, 0, 0, 0);
            a = __builtin_amdgcn_mfma_f32_16x16x32_bf16(k1, qa1, a, 0, 0, 0);
            acc[jt] = a;
        }

        if (jb < 31) {                 // issue next K/V (in flight across raw barriers)
            const float* kp = kbase + kstep * (jb + 1);
            const float* vp = vbase + kstep * (jb + 1);
            #pragma unroll
            for (int u = 0; u < 4; ++u) { kr[u] = ((const f32x4*)kp)[u]; vr[u] = ((const f32x4*)vp)[u]; }
        }

        // epilogue: attn = normalized w, Wt = bf16(w) for PV
        #pragma unroll
        for (int jt = 0; jt < 4; ++jt) {
            const int jl = jt * 16 + quad * 4;
            f32x4 s4 = acc[jt] + ev[jt];
            f32x4 w;
            w[0] = mv[jt][0] ? __expf(s4[0] * 0.125f) * inv : 0.f;
            w[1] = mv[jt][1] ? __expf(s4[1] * 0.125f) * inv : 0.f;
            w[2] = mv[jt][2] ? __expf(s4[2] * 0.125f) * inv : 0.f;
            w[3] = mv[jt][3] ? __expf(s4[3] * 0.125f) * inv : 0.f;
            *(f32x4*)(attn + srow + j0 + jl) = w;
            *(short4*)&Wt[wave][mm][jl] = make_short4(f2bf(w[0]), f2bf(w[1]), f2bf(w[2]), f2bf(w[3]));
        }

        if (jb < 31) {
            #pragma unroll
            for (int jt = 0; jt < 4; ++jt) {
                ev[jt] = *(const f32x4*)(erow + j0 + 64 + jt * 16 + quad * 4);
                mv[jt] = *(const i32x4*)(mrow + j0 + 64 + jt * 16 + quad * 4);
            }
        }

        // PV (normalized): A = Wt rows (m=i_local=mm), B = Vt (n=c). Wave-internal RAW.
        #pragma unroll
        for (int kt = 0; kt < 2; ++kt) {
            bf16x8 aw = *(const bf16x8*)&Wt[wave][mm][kt * 32 + quad * 8];
            #pragma unroll
            for (int nt = 0; nt < 4; ++nt) {
                bf16x8 bb = *(const bf16x8*)&Vt[nt * 16 + mm][kt * 32 + quad * 8];
                cacc[nt] = __builtin_amdgcn_mfma_f32_16x16x32_bf16(aw, bb, cacc[nt], 0, 0, 0);
            }
        }
        lds_barrier();                 // readers done; next iter may overwrite
    }

    // ctx: C-layout (col c = nt*16+mm, row i = quad*4+reg); already normalized
    const int irow = i0 + wave * 16 + quad * 4;
    #pragma unroll
    for (int nt = 0; nt < 4; ++nt) {
        const int c = nt * 16 + mm;
        #pragma unroll
        for (int reg = 0; reg < 4; ++reg) {
            const int i = irow + reg;
            ctx[((size_t)(b * LQ + i)) * (NH * CD) + h * CD + c] = cacc[nt][reg];
        }
    }
}

extern "C" void kernel_launch(void* const* d_in, const int* in_sizes, int n_in,
                              void* d_out, int out_size, void* d_ws, size_t ws_size,
                              hipStream_t stream) {
    const float* q    = (const float*)d_in[0];
    const float* k    = (const float*)d_in[1];
    const float* v    = (const float*)d_in[2];
    const int*   mask = (const int*)d_in[3];    // bool -> int32 per harness contract
    const float* edge = (const float*)d_in[4];

    float* out = (float*)d_out;
    float* ctx = out;                            // 2*2048*1024
    float* sc  = out + 4194304;                  // scores (B,H,L,L)
    float* at  = sc + 134217728;                 // attn   (B,H,L,L)

    k_attn<<<dim3(1024), 256, 0, stream>>>(q, k, v, mask, edge, sc, at, ctx);
}